// Round 1
// baseline (1554.612 us; speedup 1.0000x reference)
//
#include <hip/hip_runtime.h>
#include <stdint.h>

#define NE 8
#define HD 1024
#define ID 2048

typedef __attribute__((ext_vector_type(8))) short short8;
typedef __attribute__((ext_vector_type(4))) float f32x4;
typedef __attribute__((ext_vector_type(4))) unsigned short us4;

__device__ __forceinline__ unsigned short f2bf(float f) {
  uint32_t u = __builtin_bit_cast(uint32_t, f);
  u += 0x7fffu + ((u >> 16) & 1u);
  return (unsigned short)(u >> 16);
}

// ---------------- f32 -> bf16 straight convert (h) ----------------
__global__ __launch_bounds__(256) void cvt_kernel(const float* __restrict__ in,
                                                  unsigned short* __restrict__ out,
                                                  int n8) {
  int i = blockIdx.x * 256 + threadIdx.x;
  if (i >= n8) return;
  const float4* p = (const float4*)in + (size_t)i * 2;
  float4 a = p[0], b = p[1];
  unsigned short tmp[8] = {f2bf(a.x), f2bf(a.y), f2bf(a.z), f2bf(a.w),
                           f2bf(b.x), f2bf(b.y), f2bf(b.z), f2bf(b.w)};
  *(short8*)(out + (size_t)i * 8) = *(short8*)tmp;
}

// ------------- f32 [E][R][C] -> bf16 [E][C][R] transpose-convert -------------
__global__ __launch_bounds__(256) void tconv_kernel(const float* __restrict__ in,
                                                    unsigned short* __restrict__ out,
                                                    int R, int C) {
  __shared__ float t[64][65];
  int e = blockIdx.z;
  const float* ip = in + (size_t)e * R * C;
  unsigned short* op = out + (size_t)e * R * C;
  int c0 = blockIdx.x * 64, r0 = blockIdx.y * 64;
  int tid = threadIdx.x;
  int rr = tid >> 4;
  int cc = (tid & 15) * 4;
#pragma unroll
  for (int p = 0; p < 4; p++) {
    int r = p * 16 + rr;
    float4 v = *(const float4*)(ip + (size_t)(r0 + r) * C + c0 + cc);
    t[r][cc] = v.x; t[r][cc + 1] = v.y; t[r][cc + 2] = v.z; t[r][cc + 3] = v.w;
  }
  __syncthreads();
#pragma unroll
  for (int p = 0; p < 4; p++) {
    int c = p * 16 + rr;   // out row = c0+c
    int r = cc;            // 4 consecutive r
    unsigned short tmp[4];
    tmp[0] = f2bf(t[r][c]); tmp[1] = f2bf(t[r + 1][c]);
    tmp[2] = f2bf(t[r + 2][c]); tmp[3] = f2bf(t[r + 3][c]);
    *(us4*)(op + (size_t)(c0 + c) * R + r0 + r) = *(us4*)tmp;
  }
}

// ---------------- router: logits, softmax top-2, renorm, append ----------------
__global__ __launch_bounds__(256) void router_kernel(const float* __restrict__ h,
                                                     const float* __restrict__ gw,
                                                     int* __restrict__ counts,
                                                     int* __restrict__ list,
                                                     float* __restrict__ gates,
                                                     int BT) {
  __shared__ float gwl[NE * HD];  // 32 KB
  int tid = threadIdx.x;
  for (int i = tid * 4; i < NE * HD; i += 256 * 4) {
    float4 v = *(const float4*)(gw + i);
    gwl[i] = v.x; gwl[i + 1] = v.y; gwl[i + 2] = v.z; gwl[i + 3] = v.w;
  }
  __syncthreads();
  int wid = tid >> 6, lane = tid & 63;
  int t = blockIdx.x * 4 + wid;
  if (t >= BT) return;
  const float* hp = h + (size_t)t * HD;
  float hv[16];
#pragma unroll
  for (int j = 0; j < 16; j++) hv[j] = hp[lane + 64 * j];
  float acc[NE];
#pragma unroll
  for (int e = 0; e < NE; e++) {
    float s = 0.f;
#pragma unroll
    for (int j = 0; j < 16; j++) s += hv[j] * gwl[e * HD + lane + 64 * j];
    acc[e] = s;
  }
#pragma unroll
  for (int e = 0; e < NE; e++) {
#pragma unroll
    for (int off = 32; off; off >>= 1) acc[e] += __shfl_xor(acc[e], off);
  }
  if (lane == 0) {
    int i0 = 0; float m0v = acc[0];
#pragma unroll
    for (int e = 1; e < NE; e++) if (acc[e] > m0v) { m0v = acc[e]; i0 = e; }
    int i1 = -1; float m1v = -3.4e38f;
#pragma unroll
    for (int e = 0; e < NE; e++) if (e != i0 && acc[e] > m1v) { m1v = acc[e]; i1 = e; }
    float d = __expf(m1v - m0v);       // <= 1
    float g0 = 1.f / (1.f + d);
    float g1 = d / (1.f + d);
    int p0 = atomicAdd(&counts[i0], 1);
    list[i0 * BT + p0] = t * 2;     gates[i0 * BT + p0] = g0;
    int p1 = atomicAdd(&counts[i1], 1);
    list[i1 * BT + p1] = t * 2 + 1; gates[i1 * BT + p1] = g1;
  }
}

#define GLL(gsrc, ldst)                                                        \
  __builtin_amdgcn_global_load_lds(                                            \
      (const __attribute__((address_space(1))) void*)(gsrc),                   \
      (__attribute__((address_space(3))) void*)(ldst), 16, 0, 0)

// ------------- GEMM1: act[slot] = silu(h@wg) * (h@wu), gathered rows -------------
__global__ __launch_bounds__(256) void gemm1_kernel(
    const unsigned short* __restrict__ hbf,   // [BT][HD] bf16
    const unsigned short* __restrict__ wgt,   // [E][ID][HD] bf16 (N-major)
    const unsigned short* __restrict__ wut,   // [E][ID][HD]
    const int* __restrict__ counts,
    const int* __restrict__ list,
    unsigned short* __restrict__ act,         // [BT*2][ID] bf16
    int BT) {
  const int e = blockIdx.z;
  const int ne = counts[e];
  const int m0 = blockIdx.y * 128;
  if (m0 >= ne) return;
  const int n0 = blockIdx.x * 128;

  __shared__ __align__(16) unsigned short smem[128 * 64 * 3];  // 48 KB
  __shared__ int entL[128];
  unsigned short* lA = smem;
  unsigned short* lBg = smem + 128 * 64;
  unsigned short* lBu = smem + 2 * 128 * 64;

  const int tid = threadIdx.x;
  const int lane = tid & 63;
  const int w = tid >> 6;

  if (tid < 128) entL[tid] = (m0 + tid < ne) ? list[e * BT + m0 + tid] : -1;
  __syncthreads();

  const int rsub = lane >> 3;       // row within 8-row stage group
  const int csub = lane & 7;        // 16B chunk in LDS (linear)
  const int swz = csub ^ rsub;      // pre-swizzled source chunk

  const unsigned short* aSrc[4];
  const unsigned short* gSrc[4];
  const unsigned short* uSrc[4];
  const unsigned short* gB = wgt + (size_t)e * ID * HD;
  const unsigned short* uB = wut + (size_t)e * ID * HD;
#pragma unroll
  for (int i = 0; i < 4; i++) {
    int r = w * 32 + i * 8 + rsub;
    int ent = entL[r];
    int tok = ent >= 0 ? (ent >> 1) : 0;
    aSrc[i] = hbf + (size_t)tok * HD + swz * 8;
    gSrc[i] = gB + (size_t)(n0 + r) * HD + swz * 8;
    uSrc[i] = uB + (size_t)(n0 + r) * HD + swz * 8;
  }

  const int wm = w >> 1, wn = w & 1;
  f32x4 accg[4][4], accu[4][4];
#pragma unroll
  for (int m = 0; m < 4; m++)
#pragma unroll
    for (int n = 0; n < 4; n++) {
      accg[m][n] = f32x4{0.f, 0.f, 0.f, 0.f};
      accu[m][n] = f32x4{0.f, 0.f, 0.f, 0.f};
    }

  for (int kt = 0; kt < HD / 64; ++kt) {
    const int koff = kt * 64;
#pragma unroll
    for (int i = 0; i < 4; i++) {
      GLL(aSrc[i] + koff, lA + (w * 32 + i * 8) * 64);
      GLL(gSrc[i] + koff, lBg + (w * 32 + i * 8) * 64);
      GLL(uSrc[i] + koff, lBu + (w * 32 + i * 8) * 64);
    }
    __syncthreads();
#pragma unroll
    for (int kk = 0; kk < 2; kk++) {
      short8 af[4], bgf[4], buf_[4];
      const int cb = kk * 4 + (lane >> 4);
#pragma unroll
      for (int m = 0; m < 4; m++) {
        int row = wm * 64 + m * 16 + (lane & 15);
        af[m] = *(const short8*)(lA + row * 64 + ((cb ^ (row & 7)) << 3));
      }
#pragma unroll
      for (int n = 0; n < 4; n++) {
        int row = wn * 64 + n * 16 + (lane & 15);
        int off = row * 64 + ((cb ^ (row & 7)) << 3);
        bgf[n] = *(const short8*)(lBg + off);
        buf_[n] = *(const short8*)(lBu + off);
      }
#pragma unroll
      for (int m = 0; m < 4; m++)
#pragma unroll
        for (int n = 0; n < 4; n++) {
          accg[m][n] = __builtin_amdgcn_mfma_f32_16x16x32_bf16(af[m], bgf[n], accg[m][n], 0, 0, 0);
          accu[m][n] = __builtin_amdgcn_mfma_f32_16x16x32_bf16(af[m], buf_[n], accu[m][n], 0, 0, 0);
        }
    }
    __syncthreads();
  }

  // epilogue: silu(g)*u -> bf16, repack through LDS, vector store (gathered rows)
  unsigned short* actL = smem;
  const int LSTR = 136;
#pragma unroll
  for (int m = 0; m < 4; m++) {
#pragma unroll
    for (int j = 0; j < 4; j++) {
      int row = wm * 64 + m * 16 + ((lane >> 4) << 2) + j;
#pragma unroll
      for (int n = 0; n < 4; n++) {
        int col = wn * 64 + n * 16 + (lane & 15);
        float g = accg[m][n][j];
        float u = accu[m][n][j];
        float s = g / (1.f + __expf(-g));
        actL[row * LSTR + col] = f2bf(s * u);
      }
    }
  }
  __syncthreads();
#pragma unroll
  for (int i = 0; i < 8; i++) {
    int r = w * 32 + i * 4 + (lane >> 4);
    int ent = entL[r];
    if (ent >= 0) {
      short8 v = *(const short8*)(actL + r * LSTR + ((lane & 15) << 3));
      *(short8*)(act + (size_t)ent * ID + n0 + ((lane & 15) << 3)) = v;
    }
  }
}

// ------------- GEMM2: out[token] += gate * (act[slot] @ wd) -------------
__global__ __launch_bounds__(256) void gemm2_kernel(
    const unsigned short* __restrict__ act,   // [BT*2][ID] bf16
    const unsigned short* __restrict__ wdt,   // [E][HD][ID] bf16 (N-major)
    const int* __restrict__ counts,
    const int* __restrict__ list,
    const float* __restrict__ gates,
    float* __restrict__ out,                  // [BT][HD] f32 (pre-zeroed)
    int BT) {
  const int e = blockIdx.z;
  const int ne = counts[e];
  const int m0 = blockIdx.y * 128;
  if (m0 >= ne) return;
  const int n0 = blockIdx.x * 128;

  __shared__ __align__(16) unsigned short smem2[128 * 64 * 2];  // 32 KB
  __shared__ int entL[128];
  __shared__ float gL[128];
  unsigned short* lA = smem2;
  unsigned short* lB = smem2 + 128 * 64;

  const int tid = threadIdx.x;
  const int lane = tid & 63;
  const int w = tid >> 6;

  if (tid < 128) {
    bool v = (m0 + tid < ne);
    entL[tid] = v ? list[e * BT + m0 + tid] : -1;
    gL[tid] = v ? gates[e * BT + m0 + tid] : 0.f;
  }
  __syncthreads();

  const int rsub = lane >> 3;
  const int csub = lane & 7;
  const int swz = csub ^ rsub;

  const unsigned short* aSrc[4];
  const unsigned short* bSrc[4];
  const unsigned short* dB = wdt + (size_t)e * HD * ID;
#pragma unroll
  for (int i = 0; i < 4; i++) {
    int r = w * 32 + i * 8 + rsub;
    int ent = entL[r];
    int slot = ent >= 0 ? ent : 0;
    aSrc[i] = act + (size_t)slot * ID + swz * 8;
    bSrc[i] = dB + (size_t)(n0 + r) * ID + swz * 8;
  }

  const int wm = w >> 1, wn = w & 1;
  f32x4 acc[4][4];
#pragma unroll
  for (int m = 0; m < 4; m++)
#pragma unroll
    for (int n = 0; n < 4; n++) acc[m][n] = f32x4{0.f, 0.f, 0.f, 0.f};

  for (int kt = 0; kt < ID / 64; ++kt) {
    const int koff = kt * 64;
#pragma unroll
    for (int i = 0; i < 4; i++) {
      GLL(aSrc[i] + koff, lA + (w * 32 + i * 8) * 64);
      GLL(bSrc[i] + koff, lB + (w * 32 + i * 8) * 64);
    }
    __syncthreads();
#pragma unroll
    for (int kk = 0; kk < 2; kk++) {
      short8 af[4], bf_[4];
      const int cb = kk * 4 + (lane >> 4);
#pragma unroll
      for (int m = 0; m < 4; m++) {
        int row = wm * 64 + m * 16 + (lane & 15);
        af[m] = *(const short8*)(lA + row * 64 + ((cb ^ (row & 7)) << 3));
      }
#pragma unroll
      for (int n = 0; n < 4; n++) {
        int row = wn * 64 + n * 16 + (lane & 15);
        bf_[n] = *(const short8*)(lB + row * 64 + ((cb ^ (row & 7)) << 3));
      }
#pragma unroll
      for (int m = 0; m < 4; m++)
#pragma unroll
        for (int n = 0; n < 4; n++)
          acc[m][n] = __builtin_amdgcn_mfma_f32_16x16x32_bf16(af[m], bf_[n], acc[m][n], 0, 0, 0);
    }
    __syncthreads();
  }

#pragma unroll
  for (int m = 0; m < 4; m++) {
#pragma unroll
    for (int j = 0; j < 4; j++) {
      int row = wm * 64 + m * 16 + ((lane >> 4) << 2) + j;
      int ent = entL[row];
      if (ent >= 0) {
        float gt = gL[row];
        float* op = out + (size_t)(ent >> 1) * HD + n0;
#pragma unroll
        for (int n = 0; n < 4; n++) {
          int col = wn * 64 + n * 16 + (lane & 15);
          atomicAdd(op + col, acc[m][n][j] * gt);
        }
      }
    }
  }
}

extern "C" void kernel_launch(void* const* d_in, const int* in_sizes, int n_in,
                              void* d_out, int out_size, void* d_ws, size_t ws_size,
                              hipStream_t stream) {
  (void)n_in; (void)ws_size;
  const float* h  = (const float*)d_in[0];
  const float* gw = (const float*)d_in[1];
  const float* wg = (const float*)d_in[2];
  const float* wu = (const float*)d_in[3];
  const float* wd = (const float*)d_in[4];
  float* out = (float*)d_out;
  const int BT = in_sizes[0] / HD;

  char* ws = (char*)d_ws;
  size_t off = 0;
  auto alloc = [&](size_t b) -> char* {
    char* p = ws + off;
    off = (off + b + 255) & ~(size_t)255;
    return p;
  };
  unsigned short* hbf = (unsigned short*)alloc((size_t)BT * HD * 2);
  unsigned short* wgt = (unsigned short*)alloc((size_t)NE * HD * ID * 2);
  unsigned short* wut = (unsigned short*)alloc((size_t)NE * HD * ID * 2);
  unsigned short* wdt = (unsigned short*)alloc((size_t)NE * HD * ID * 2);
  unsigned short* act = (unsigned short*)alloc((size_t)BT * 2 * ID * 2);
  int* counts = (int*)alloc(NE * 4);
  int* list = (int*)alloc((size_t)NE * BT * 4);
  float* gates = (float*)alloc((size_t)NE * BT * 4);

  hipMemsetAsync(counts, 0, NE * 4, stream);
  hipMemsetAsync(out, 0, (size_t)out_size * 4, stream);

  cvt_kernel<<<(BT * HD / 8 + 255) / 256, 256, 0, stream>>>(h, hbf, BT * HD / 8);
  tconv_kernel<<<dim3(ID / 64, HD / 64, NE), 256, 0, stream>>>(wg, wgt, HD, ID);
  tconv_kernel<<<dim3(ID / 64, HD / 64, NE), 256, 0, stream>>>(wu, wut, HD, ID);
  tconv_kernel<<<dim3(HD / 64, ID / 64, NE), 256, 0, stream>>>(wd, wdt, ID, HD);
  router_kernel<<<BT / 4, 256, 0, stream>>>(h, gw, counts, list, gates, BT);
  gemm1_kernel<<<dim3(ID / 128, BT / 128, NE), 256, 0, stream>>>(hbf, wgt, wut, counts, list, act, BT);
  gemm2_kernel<<<dim3(HD / 128, BT / 128, NE), 256, 0, stream>>>(act, wdt, counts, list, gates, out, BT);
}

// Round 2
// 1259.942 us; speedup vs baseline: 1.2339x; 1.2339x over previous
//
#include <hip/hip_runtime.h>
#include <stdint.h>

#define NE 8
#define HD 1024
#define ID 2048

typedef __attribute__((ext_vector_type(8))) short short8;
typedef __attribute__((ext_vector_type(4))) float f32x4;
typedef __attribute__((ext_vector_type(4))) unsigned short us4;

__device__ __forceinline__ unsigned short f2bf(float f) {
  uint32_t u = __builtin_bit_cast(uint32_t, f);
  u += 0x7fffu + ((u >> 16) & 1u);
  return (unsigned short)(u >> 16);
}
__device__ __forceinline__ float bf2f(unsigned short s) {
  uint32_t u = ((uint32_t)s) << 16;
  return __builtin_bit_cast(float, u);
}

// ---------------- f32 -> bf16 straight convert (h) ----------------
__global__ __launch_bounds__(256) void cvt_kernel(const float* __restrict__ in,
                                                  unsigned short* __restrict__ out,
                                                  int n8) {
  int i = blockIdx.x * 256 + threadIdx.x;
  if (i >= n8) return;
  const float4* p = (const float4*)in + (size_t)i * 2;
  float4 a = p[0], b = p[1];
  unsigned short tmp[8] = {f2bf(a.x), f2bf(a.y), f2bf(a.z), f2bf(a.w),
                           f2bf(b.x), f2bf(b.y), f2bf(b.z), f2bf(b.w)};
  *(short8*)(out + (size_t)i * 8) = *(short8*)tmp;
}

// ------------- f32 [E][R][C] -> bf16 [E][C][R] transpose-convert -------------
__global__ __launch_bounds__(256) void tconv_kernel(const float* __restrict__ in,
                                                    unsigned short* __restrict__ out,
                                                    int R, int C) {
  __shared__ float t[64][65];
  int e = blockIdx.z;
  const float* ip = in + (size_t)e * R * C;
  unsigned short* op = out + (size_t)e * R * C;
  int c0 = blockIdx.x * 64, r0 = blockIdx.y * 64;
  int tid = threadIdx.x;
  int rr = tid >> 4;
  int cc = (tid & 15) * 4;
#pragma unroll
  for (int p = 0; p < 4; p++) {
    int r = p * 16 + rr;
    float4 v = *(const float4*)(ip + (size_t)(r0 + r) * C + c0 + cc);
    t[r][cc] = v.x; t[r][cc + 1] = v.y; t[r][cc + 2] = v.z; t[r][cc + 3] = v.w;
  }
  __syncthreads();
#pragma unroll
  for (int p = 0; p < 4; p++) {
    int c = p * 16 + rr;
    int r = cc;
    unsigned short tmp[4];
    tmp[0] = f2bf(t[r][c]); tmp[1] = f2bf(t[r + 1][c]);
    tmp[2] = f2bf(t[r + 2][c]); tmp[3] = f2bf(t[r + 3][c]);
    *(us4*)(op + (size_t)(c0 + c) * R + r0 + r) = *(us4*)tmp;
  }
}

// ---------------- router ----------------
__global__ __launch_bounds__(256) void router_kernel(const float* __restrict__ h,
                                                     const float* __restrict__ gw,
                                                     int* __restrict__ counts,
                                                     int* __restrict__ list,
                                                     float* __restrict__ gates,
                                                     int BT) {
  __shared__ float gwl[NE * HD];
  int tid = threadIdx.x;
  for (int i = tid * 4; i < NE * HD; i += 256 * 4) {
    float4 v = *(const float4*)(gw + i);
    gwl[i] = v.x; gwl[i + 1] = v.y; gwl[i + 2] = v.z; gwl[i + 3] = v.w;
  }
  __syncthreads();
  int wid = tid >> 6, lane = tid & 63;
  int t = blockIdx.x * 4 + wid;
  if (t >= BT) return;
  const float* hp = h + (size_t)t * HD;
  float hv[16];
#pragma unroll
  for (int j = 0; j < 16; j++) hv[j] = hp[lane + 64 * j];
  float acc[NE];
#pragma unroll
  for (int e = 0; e < NE; e++) {
    float s = 0.f;
#pragma unroll
    for (int j = 0; j < 16; j++) s += hv[j] * gwl[e * HD + lane + 64 * j];
    acc[e] = s;
  }
#pragma unroll
  for (int e = 0; e < NE; e++) {
#pragma unroll
    for (int off = 32; off; off >>= 1) acc[e] += __shfl_xor(acc[e], off);
  }
  if (lane == 0) {
    int i0 = 0; float m0v = acc[0];
#pragma unroll
    for (int e = 1; e < NE; e++) if (acc[e] > m0v) { m0v = acc[e]; i0 = e; }
    int i1 = -1; float m1v = -3.4e38f;
#pragma unroll
    for (int e = 0; e < NE; e++) if (e != i0 && acc[e] > m1v) { m1v = acc[e]; i1 = e; }
    float d = __expf(m1v - m0v);
    float g0 = 1.f / (1.f + d);
    float g1 = d / (1.f + d);
    int p0 = atomicAdd(&counts[i0], 1);
    list[i0 * BT + p0] = t * 2;     gates[i0 * BT + p0] = g0;
    int p1 = atomicAdd(&counts[i1], 1);
    list[i1 * BT + p1] = t * 2 + 1; gates[i1 * BT + p1] = g1;
  }
}

#define GLL(gsrc, ldst)                                                        \
  __builtin_amdgcn_global_load_lds(                                            \
      (const __attribute__((address_space(1))) void*)(gsrc),                   \
      (__attribute__((address_space(3))) void*)(ldst), 16, 0, 0)

// ------------- GEMM1: act[slot] = silu(h@wg) * (h@wu), gathered rows -------------
// 512 thr, BM=256, BN=128 (dual gate/up), dbuf 2-phase, 8 waves 2m x 4n,
// wave tile 128M x 32N per acc-type.
__global__ __launch_bounds__(512, 2) void gemm1_kernel(
    const unsigned short* __restrict__ hbf,   // [BT][HD]
    const unsigned short* __restrict__ wgt,   // [E][ID][HD]
    const unsigned short* __restrict__ wut,   // [E][ID][HD]
    const int* __restrict__ counts,
    const int* __restrict__ list,
    unsigned short* __restrict__ act,         // [BT*2][ID]
    int BT) {
  const int e = blockIdx.z;
  const int ne = counts[e];
  const int m0 = blockIdx.y * 256;
  if (m0 >= ne) return;
  const int n0 = blockIdx.x * 128;

  // dbuf: per buf = A 256x64 (16384) | Bg 128x64 (8192) | Bu 128x64 (8192) = 32768 elems
  __shared__ __align__(16) unsigned short smem[2 * 32768];  // 128 KB
  __shared__ int entL[256];

  const int tid = threadIdx.x;
  const int lane = tid & 63;
  const int w = tid >> 6;

  if (tid < 256) entL[tid] = (m0 + tid < ne) ? list[e * BT + m0 + tid] : -1;
  __syncthreads();

  const int rsub = lane >> 3;            // 0..7
  const int swz = (lane & 7) ^ rsub;     // pre-swizzled source chunk

  const unsigned short* aA[4];
  const unsigned short* aG[2];
  const unsigned short* aU[2];
  const unsigned short* gB = wgt + (size_t)e * ID * HD;
  const unsigned short* uB = wut + (size_t)e * ID * HD;
#pragma unroll
  for (int i = 0; i < 4; i++) {
    int r = i * 64 + w * 8 + rsub;
    int ent = entL[r];
    int tok = ent >= 0 ? (ent >> 1) : 0;
    aA[i] = hbf + (size_t)tok * HD + swz * 8;
  }
#pragma unroll
  for (int i = 0; i < 2; i++) {
    int r = i * 64 + w * 8 + rsub;
    aG[i] = gB + (size_t)(n0 + r) * HD + swz * 8;
    aU[i] = uB + (size_t)(n0 + r) * HD + swz * 8;
  }

  const int wm = w >> 2, wn = w & 3;     // 2m x 4n
  f32x4 accg[8][2], accu[8][2];
#pragma unroll
  for (int m = 0; m < 8; m++)
#pragma unroll
    for (int n = 0; n < 2; n++) {
      accg[m][n] = f32x4{0.f, 0.f, 0.f, 0.f};
      accu[m][n] = f32x4{0.f, 0.f, 0.f, 0.f};
    }

  auto stage = [&](int b, int koff) {
    unsigned short* base = smem + b * 32768;
#pragma unroll
    for (int i = 0; i < 4; i++)
      GLL(aA[i] + koff, base + (i * 64 + w * 8) * 64);
#pragma unroll
    for (int i = 0; i < 2; i++) {
      GLL(aG[i] + koff, base + 16384 + (i * 64 + w * 8) * 64);
      GLL(aU[i] + koff, base + 24576 + (i * 64 + w * 8) * 64);
    }
  };

  stage(0, 0);
  __syncthreads();
  int cur = 0;
#pragma unroll 1
  for (int kt = 0; kt < HD / 64; ++kt) {
    if (kt + 1 < HD / 64) stage(cur ^ 1, (kt + 1) * 64);
    const unsigned short* lA = smem + cur * 32768;
    const unsigned short* lBg = lA + 16384;
    const unsigned short* lBu = lA + 24576;
#pragma unroll
    for (int kk = 0; kk < 2; kk++) {
      const int cb = kk * 4 + (lane >> 4);
      short8 af[8], bg[2], bu[2];
#pragma unroll
      for (int m = 0; m < 8; m++) {
        int row = wm * 128 + m * 16 + (lane & 15);
        af[m] = *(const short8*)(lA + row * 64 + ((cb ^ (row & 7)) << 3));
      }
#pragma unroll
      for (int n = 0; n < 2; n++) {
        int row = wn * 32 + n * 16 + (lane & 15);
        int off = row * 64 + ((cb ^ (row & 7)) << 3);
        bg[n] = *(const short8*)(lBg + off);
        bu[n] = *(const short8*)(lBu + off);
      }
#pragma unroll
      for (int m = 0; m < 8; m++)
#pragma unroll
        for (int n = 0; n < 2; n++) {
          accg[m][n] = __builtin_amdgcn_mfma_f32_16x16x32_bf16(af[m], bg[n], accg[m][n], 0, 0, 0);
          accu[m][n] = __builtin_amdgcn_mfma_f32_16x16x32_bf16(af[m], bu[n], accu[m][n], 0, 0, 0);
        }
    }
    __syncthreads();
    cur ^= 1;
  }

  // epilogue: silu(g)*u -> bf16, LDS repack, coalesced gathered store
  unsigned short* actL = smem;
  const int LSTR = 136;
#pragma unroll
  for (int m = 0; m < 8; m++) {
#pragma unroll
    for (int j = 0; j < 4; j++) {
      int row = wm * 128 + m * 16 + ((lane >> 4) << 2) + j;
#pragma unroll
      for (int n = 0; n < 2; n++) {
        int col = wn * 32 + n * 16 + (lane & 15);
        float g = accg[m][n][j];
        float u = accu[m][n][j];
        float s = g / (1.f + __expf(-g));
        actL[row * LSTR + col] = f2bf(s * u);
      }
    }
  }
  __syncthreads();
#pragma unroll
  for (int i = 0; i < 8; i++) {
    int r = i * 32 + (tid >> 4);
    int ent = entL[r];
    if (ent >= 0) {
      int chunk = tid & 15;
      short8 v = *(const short8*)(actL + r * LSTR + chunk * 8);
      *(short8*)(act + (size_t)ent * ID + n0 + chunk * 8) = v;
    }
  }
}

// ------------- GEMM2: y[slot] = gate * (act[slot] @ wd), plain stores -------------
// 512 thr, BM=256, BN=256, dbuf 2-phase, 8 waves 2m x 4n, wave tile 128M x 64N.
__global__ __launch_bounds__(512, 2) void gemm2_kernel(
    const unsigned short* __restrict__ act,   // [BT*2][ID]
    const unsigned short* __restrict__ wdt,   // [E][HD][ID]
    const int* __restrict__ counts,
    const int* __restrict__ list,
    const float* __restrict__ gates,
    unsigned short* __restrict__ yb,          // [BT*2][HD] bf16, gate-scaled
    int BT) {
  const int e = blockIdx.z;
  const int ne = counts[e];
  const int m0 = blockIdx.y * 256;
  if (m0 >= ne) return;
  const int n0 = blockIdx.x * 256;

  // dbuf: per buf = A 256x64 (16384) | B 256x64 (16384) = 32768 elems
  __shared__ __align__(16) unsigned short smem[2 * 32768];  // 128 KB
  __shared__ int entL[256];
  __shared__ float gL[256];

  const int tid = threadIdx.x;
  const int lane = tid & 63;
  const int w = tid >> 6;

  if (tid < 256) {
    bool v = (m0 + tid < ne);
    entL[tid] = v ? list[e * BT + m0 + tid] : -1;
    gL[tid] = v ? gates[e * BT + m0 + tid] : 0.f;
  }
  __syncthreads();

  const int rsub = lane >> 3;
  const int swz = (lane & 7) ^ rsub;

  const unsigned short* aA[4];
  const unsigned short* aB[4];
  const unsigned short* dB = wdt + (size_t)e * HD * ID;
#pragma unroll
  for (int i = 0; i < 4; i++) {
    int r = i * 64 + w * 8 + rsub;
    int ent = entL[r];
    int slot = ent >= 0 ? ent : 0;
    aA[i] = act + (size_t)slot * ID + swz * 8;
    aB[i] = dB + (size_t)(n0 + r) * ID + swz * 8;
  }

  const int wm = w >> 2, wn = w & 3;
  f32x4 acc[8][4];
#pragma unroll
  for (int m = 0; m < 8; m++)
#pragma unroll
    for (int n = 0; n < 4; n++) acc[m][n] = f32x4{0.f, 0.f, 0.f, 0.f};

  auto stage = [&](int b, int koff) {
    unsigned short* base = smem + b * 32768;
#pragma unroll
    for (int i = 0; i < 4; i++) {
      GLL(aA[i] + koff, base + (i * 64 + w * 8) * 64);
      GLL(aB[i] + koff, base + 16384 + (i * 64 + w * 8) * 64);
    }
  };

  stage(0, 0);
  __syncthreads();
  int cur = 0;
#pragma unroll 1
  for (int kt = 0; kt < ID / 64; ++kt) {
    if (kt + 1 < ID / 64) stage(cur ^ 1, (kt + 1) * 64);
    const unsigned short* lA = smem + cur * 32768;
    const unsigned short* lB = lA + 16384;
#pragma unroll
    for (int kk = 0; kk < 2; kk++) {
      const int cb = kk * 4 + (lane >> 4);
      short8 af[8], bf_[4];
#pragma unroll
      for (int m = 0; m < 8; m++) {
        int row = wm * 128 + m * 16 + (lane & 15);
        af[m] = *(const short8*)(lA + row * 64 + ((cb ^ (row & 7)) << 3));
      }
#pragma unroll
      for (int n = 0; n < 4; n++) {
        int row = wn * 64 + n * 16 + (lane & 15);
        bf_[n] = *(const short8*)(lB + row * 64 + ((cb ^ (row & 7)) << 3));
      }
#pragma unroll
      for (int m = 0; m < 8; m++)
#pragma unroll
        for (int n = 0; n < 4; n++)
          acc[m][n] = __builtin_amdgcn_mfma_f32_16x16x32_bf16(af[m], bf_[n], acc[m][n], 0, 0, 0);
    }
    __syncthreads();
    cur ^= 1;
  }

  // epilogue: scale by gate, bf16, 2-pass LDS repack (128 rows each), coalesced store
  unsigned short* yL = smem;
  const int LSTR2 = 264;  // 256 cols + 8 pad
#pragma unroll 1
  for (int p = 0; p < 2; p++) {
    if (wm == p) {
#pragma unroll
      for (int m = 0; m < 8; m++) {
#pragma unroll
        for (int j = 0; j < 4; j++) {
          int row = m * 16 + ((lane >> 4) << 2) + j;  // 0..127 local
          float gt = gL[p * 128 + row];
#pragma unroll
          for (int n = 0; n < 4; n++) {
            int col = wn * 64 + n * 16 + (lane & 15);
            yL[row * LSTR2 + col] = f2bf(acc[m][n][j] * gt);
          }
        }
      }
    }
    __syncthreads();
#pragma unroll
    for (int i = 0; i < 8; i++) {
      int r = i * 16 + (tid >> 5);
      int ent = entL[p * 128 + r];
      if (ent >= 0) {
        int chunk = tid & 31;
        short8 v = *(const short8*)(yL + r * LSTR2 + chunk * 8);
        *(short8*)(yb + (size_t)ent * HD + n0 + chunk * 8) = v;
      }
    }
    __syncthreads();
  }
}

// ------------- combine: out[t] = y[2t] + y[2t+1] (fp32) -------------
__global__ __launch_bounds__(256) void combine_kernel(const unsigned short* __restrict__ y,
                                                      float* __restrict__ out, int n8) {
  int i = blockIdx.x * 256 + threadIdx.x;
  if (i >= n8) return;
  int t = i >> 7;            // HD/8 = 128 chunks per token
  int c = (i & 127) * 8;
  short8 a = *(const short8*)(y + (size_t)(t * 2) * HD + c);
  short8 b = *(const short8*)(y + (size_t)(t * 2 + 1) * HD + c);
  float o[8];
#pragma unroll
  for (int j = 0; j < 8; j++)
    o[j] = bf2f((unsigned short)a[j]) + bf2f((unsigned short)b[j]);
  float* op = out + (size_t)t * HD + c;
  *(float4*)op = float4{o[0], o[1], o[2], o[3]};
  *(float4*)(op + 4) = float4{o[4], o[5], o[6], o[7]};
}

extern "C" void kernel_launch(void* const* d_in, const int* in_sizes, int n_in,
                              void* d_out, int out_size, void* d_ws, size_t ws_size,
                              hipStream_t stream) {
  (void)n_in; (void)ws_size; (void)out_size;
  const float* h  = (const float*)d_in[0];
  const float* gw = (const float*)d_in[1];
  const float* wg = (const float*)d_in[2];
  const float* wu = (const float*)d_in[3];
  const float* wd = (const float*)d_in[4];
  float* out = (float*)d_out;
  const int BT = in_sizes[0] / HD;

  char* ws = (char*)d_ws;
  size_t off = 0;
  auto alloc = [&](size_t b) -> char* {
    char* p = ws + off;
    off = (off + b + 255) & ~(size_t)255;
    return p;
  };
  unsigned short* hbf = (unsigned short*)alloc((size_t)BT * HD * 2);
  unsigned short* wgt = (unsigned short*)alloc((size_t)NE * HD * ID * 2);
  unsigned short* wut = (unsigned short*)alloc((size_t)NE * HD * ID * 2);
  unsigned short* wdt = (unsigned short*)alloc((size_t)NE * HD * ID * 2);
  unsigned short* act = (unsigned short*)alloc((size_t)BT * 2 * ID * 2);
  int* counts = (int*)alloc(NE * 4);
  int* list = (int*)alloc((size_t)NE * BT * 4);
  float* gates = (float*)alloc((size_t)NE * BT * 4);
  // y ([BT*2][HD] bf16 = 64 MB) aliases wgt+wut (dead after gemm1; rewritten
  // by tconv every call, so no cross-call state).
  unsigned short* yb = wgt;

  hipMemsetAsync(counts, 0, NE * 4, stream);

  cvt_kernel<<<(BT * HD / 8 + 255) / 256, 256, 0, stream>>>(h, hbf, BT * HD / 8);
  tconv_kernel<<<dim3(ID / 64, HD / 64, NE), 256, 0, stream>>>(wg, wgt, HD, ID);
  tconv_kernel<<<dim3(ID / 64, HD / 64, NE), 256, 0, stream>>>(wu, wut, HD, ID);
  tconv_kernel<<<dim3(HD / 64, ID / 64, NE), 256, 0, stream>>>(wd, wdt, ID, HD);
  router_kernel<<<BT / 4, 256, 0, stream>>>(h, gw, counts, list, gates, BT);
  gemm1_kernel<<<dim3(ID / 128, (BT + 255) / 256, NE), 512, 0, stream>>>(hbf, wgt, wut, counts, list, act, BT);
  gemm2_kernel<<<dim3(HD / 256, (BT + 255) / 256, NE), 512, 0, stream>>>(act, wdt, counts, list, gates, yb, BT);
  combine_kernel<<<(BT * HD / 8 + 255) / 256, 256, 0, stream>>>(yb, out, BT * HD / 8);
}

// Round 4
// 1197.757 us; speedup vs baseline: 1.2979x; 1.0519x over previous
//
#include <hip/hip_runtime.h>
#include <stdint.h>

#define NE 8
#define HD 1024
#define ID 2048

typedef __attribute__((ext_vector_type(8))) short short8;
typedef __attribute__((ext_vector_type(4))) float f32x4;
typedef __attribute__((ext_vector_type(4))) unsigned short us4;

__device__ __forceinline__ unsigned short f2bf(float f) {
  uint32_t u = __builtin_bit_cast(uint32_t, f);
  u += 0x7fffu + ((u >> 16) & 1u);
  return (unsigned short)(u >> 16);
}
__device__ __forceinline__ float bf2f(unsigned short s) {
  uint32_t u = ((uint32_t)s) << 16;
  return __builtin_bit_cast(float, u);
}

// ---------------- f32 -> bf16 straight convert (h) ----------------
__global__ __launch_bounds__(256) void cvt_kernel(const float* __restrict__ in,
                                                  unsigned short* __restrict__ out,
                                                  int n8) {
  int i = blockIdx.x * 256 + threadIdx.x;
  if (i >= n8) return;
  const float4* p = (const float4*)in + (size_t)i * 2;
  float4 a = p[0], b = p[1];
  unsigned short tmp[8] = {f2bf(a.x), f2bf(a.y), f2bf(a.z), f2bf(a.w),
                           f2bf(b.x), f2bf(b.y), f2bf(b.z), f2bf(b.w)};
  *(short8*)(out + (size_t)i * 8) = *(short8*)tmp;
}

// ------------- f32 [E][R][C] -> bf16 [E][C][R] transpose-convert -------------
__global__ __launch_bounds__(256) void tconv_kernel(const float* __restrict__ in,
                                                    unsigned short* __restrict__ out,
                                                    int R, int C) {
  __shared__ float t[64][65];
  int e = blockIdx.z;
  const float* ip = in + (size_t)e * R * C;
  unsigned short* op = out + (size_t)e * R * C;
  int c0 = blockIdx.x * 64, r0 = blockIdx.y * 64;
  int tid = threadIdx.x;
  int rr = tid >> 4;
  int cc = (tid & 15) * 4;
#pragma unroll
  for (int p = 0; p < 4; p++) {
    int r = p * 16 + rr;
    float4 v = *(const float4*)(ip + (size_t)(r0 + r) * C + c0 + cc);
    t[r][cc] = v.x; t[r][cc + 1] = v.y; t[r][cc + 2] = v.z; t[r][cc + 3] = v.w;
  }
  __syncthreads();
#pragma unroll
  for (int p = 0; p < 4; p++) {
    int c = p * 16 + rr;
    int r = cc;
    unsigned short tmp[4];
    tmp[0] = f2bf(t[r][c]); tmp[1] = f2bf(t[r + 1][c]);
    tmp[2] = f2bf(t[r + 2][c]); tmp[3] = f2bf(t[r + 3][c]);
    *(us4*)(op + (size_t)(c0 + c) * R + r0 + r) = *(us4*)tmp;
  }
}

// ---------------- router ----------------
__global__ __launch_bounds__(256) void router_kernel(const float* __restrict__ h,
                                                     const float* __restrict__ gw,
                                                     int* __restrict__ counts,
                                                     int* __restrict__ list,
                                                     float* __restrict__ gates,
                                                     int BT) {
  __shared__ float gwl[NE * HD];
  int tid = threadIdx.x;
  for (int i = tid * 4; i < NE * HD; i += 256 * 4) {
    float4 v = *(const float4*)(gw + i);
    gwl[i] = v.x; gwl[i + 1] = v.y; gwl[i + 2] = v.z; gwl[i + 3] = v.w;
  }
  __syncthreads();
  int wid = tid >> 6, lane = tid & 63;
  int t = blockIdx.x * 4 + wid;
  if (t >= BT) return;
  const float* hp = h + (size_t)t * HD;
  float hv[16];
#pragma unroll
  for (int j = 0; j < 16; j++) hv[j] = hp[lane + 64 * j];
  float acc[NE];
#pragma unroll
  for (int e = 0; e < NE; e++) {
    float s = 0.f;
#pragma unroll
    for (int j = 0; j < 16; j++) s += hv[j] * gwl[e * HD + lane + 64 * j];
    acc[e] = s;
  }
#pragma unroll
  for (int e = 0; e < NE; e++) {
#pragma unroll
    for (int off = 32; off; off >>= 1) acc[e] += __shfl_xor(acc[e], off);
  }
  if (lane == 0) {
    int i0 = 0; float m0v = acc[0];
#pragma unroll
    for (int e = 1; e < NE; e++) if (acc[e] > m0v) { m0v = acc[e]; i0 = e; }
    int i1 = -1; float m1v = -3.4e38f;
#pragma unroll
    for (int e = 0; e < NE; e++) if (e != i0 && acc[e] > m1v) { m1v = acc[e]; i1 = e; }
    float d = __expf(m1v - m0v);
    float g0 = 1.f / (1.f + d);
    float g1 = d / (1.f + d);
    int p0 = atomicAdd(&counts[i0], 1);
    list[i0 * BT + p0] = t * 2;     gates[i0 * BT + p0] = g0;
    int p1 = atomicAdd(&counts[i1], 1);
    list[i1 * BT + p1] = t * 2 + 1; gates[i1 * BT + p1] = g1;
  }
}

#define GLL(gsrc, ldst)                                                        \
  __builtin_amdgcn_global_load_lds(                                            \
      (const __attribute__((address_space(1))) void*)(gsrc),                   \
      (__attribute__((address_space(3))) void*)(ldst), 16, 0, 0)

#define WAITV4 asm volatile("s_waitcnt vmcnt(4)" ::: "memory")
#define WAITV2 asm volatile("s_waitcnt vmcnt(2)" ::: "memory")
#define WAITV0 asm volatile("s_waitcnt vmcnt(0)" ::: "memory")
#define BARC()  do { __builtin_amdgcn_s_barrier(); asm volatile("" ::: "memory"); } while (0)
#define PRIO1() __builtin_amdgcn_s_setprio(1)
#define PRIO0() __builtin_amdgcn_s_setprio(0)

// ------------- GEMM1: act[slot] = silu(h@wg)*(h@wu) -------------
// 512 thr, BM=256, BN=128 dual, 8 waves 2m x 4n, wave 128M x 32N per type.
// 4-phase counted-vmcnt. Stage units == phase read-sets:
//   A half h = rows {h*64+[0,63]} U {128+h*64+[0,63]}  (af0 reads h=0, af1 h=1)
//   G, U full 128-row tiles.
// Per-tile stage (into nxt): P0:Ah0  P1:G  P2:U  P3:Ah1. Steady waits vmcnt(4).
__global__ __launch_bounds__(512, 2) void gemm1_kernel(
    const unsigned short* __restrict__ hbf,
    const unsigned short* __restrict__ wgt,
    const unsigned short* __restrict__ wut,
    const int* __restrict__ counts,
    const int* __restrict__ list,
    unsigned short* __restrict__ act,
    int BT) {
  const int e = blockIdx.z;
  const int ne = counts[e];
  const int m0 = blockIdx.y * 256;
  if (m0 >= ne) return;
  const int n0 = blockIdx.x * 128;

  __shared__ __align__(16) unsigned short smem[2 * 32768];  // 128 KB
  __shared__ int entL[256];

  const int tid = threadIdx.x;
  const int lane = tid & 63;
  const int w = tid >> 6;

  if (tid < 256) entL[tid] = (m0 + tid < ne) ? list[e * BT + m0 + tid] : -1;
  __syncthreads();

  const int rsub = lane >> 3;
  const int swz = (lane & 7) ^ rsub;

  const unsigned short* aA[4];   // aA[i]: rows i*64 + w*8 + rsub
  const unsigned short* aG[2];
  const unsigned short* aU[2];
  const unsigned short* gB = wgt + (size_t)e * ID * HD;
  const unsigned short* uB = wut + (size_t)e * ID * HD;
#pragma unroll
  for (int i = 0; i < 4; i++) {
    int r = i * 64 + w * 8 + rsub;
    int ent = entL[r];
    int tok = ent >= 0 ? (ent >> 1) : 0;
    aA[i] = hbf + (size_t)tok * HD + swz * 8;
  }
#pragma unroll
  for (int i = 0; i < 2; i++) {
    int r = i * 64 + w * 8 + rsub;
    aG[i] = gB + (size_t)(n0 + r) * HD + swz * 8;
    aU[i] = uB + (size_t)(n0 + r) * HD + swz * 8;
  }

  const int wm = w >> 2, wn = w & 3;
  const int r16 = lane & 15, c4 = lane >> 4;

  f32x4 accg[8][2], accu[8][2];
#pragma unroll
  for (int m = 0; m < 8; m++)
#pragma unroll
    for (int n = 0; n < 2; n++) {
      accg[m][n] = f32x4{0.f, 0.f, 0.f, 0.f};
      accu[m][n] = f32x4{0.f, 0.f, 0.f, 0.f};
    }

  // A half h: rows {h*64..h*64+63} and {128+h*64..128+h*64+63}
  auto stA = [&](int b, int h, int koff) {
    unsigned short* base = smem + b * 32768;
    GLL(aA[h] + koff,     base + ((h * 64) + w * 8) * 64);
    GLL(aA[h + 2] + koff, base + ((128 + h * 64) + w * 8) * 64);
  };
  auto stG = [&](int b, int koff) {
    unsigned short* base = smem + b * 32768 + 16384 + (w * 8) * 64;
    GLL(aG[0] + koff, base);
    GLL(aG[1] + koff, base + 4096);
  };
  auto stU = [&](int b, int koff) {
    unsigned short* base = smem + b * 32768 + 24576 + (w * 8) * 64;
    GLL(aU[0] + koff, base);
    GLL(aU[1] + koff, base + 4096);
  };

  // prologue: FIFO order Ah0(0), G(0), U(0), Ah1(0) = 8 loads
  stA(0, 0, 0); stG(0, 0); stU(0, 0); stA(0, 1, 0);

#pragma unroll 1
  for (int t = 0; t < HD / 64; ++t) {
    const int cur = t & 1, nxt = cur ^ 1;
    const int kn = t * 64 + 64;
    const bool more = (t < HD / 64 - 1);
    const unsigned short* lA = smem + cur * 32768;
    const unsigned short* lBg = lA + 16384;
    const unsigned short* lBu = lA + 24576;

    short8 af0[2][4], af1[2][4], bg[2][2], bu[2][2];

    // ---- P0: needs Ah0(t)+G(t); MFMA(mh0,gate); stage Ah0(t+1) ----
    WAITV4; BARC();
#pragma unroll
    for (int kk = 0; kk < 2; kk++) {
      const int cb = kk * 4 + c4;
#pragma unroll
      for (int m = 0; m < 4; m++) {
        int row = wm * 128 + m * 16 + r16;   // in A half0
        af0[kk][m] = *(const short8*)(lA + row * 64 + ((cb ^ (row & 7)) << 3));
      }
#pragma unroll
      for (int n = 0; n < 2; n++) {
        int row = wn * 32 + n * 16 + r16;
        bg[kk][n] = *(const short8*)(lBg + row * 64 + ((cb ^ (row & 7)) << 3));
      }
    }
    if (more) stA(nxt, 0, kn);
    PRIO1();
#pragma unroll
    for (int kk = 0; kk < 2; kk++)
#pragma unroll
      for (int m = 0; m < 4; m++)
#pragma unroll
        for (int n = 0; n < 2; n++)
          accg[m][n] = __builtin_amdgcn_mfma_f32_16x16x32_bf16(af0[kk][m], bg[kk][n], accg[m][n], 0, 0, 0);
    PRIO0();

    // ---- P1: needs U(t); MFMA(mh0,up); stage G(t+1) ----
    if (more) { WAITV4; } else { WAITV2; }
    BARC();
#pragma unroll
    for (int kk = 0; kk < 2; kk++) {
      const int cb = kk * 4 + c4;
#pragma unroll
      for (int n = 0; n < 2; n++) {
        int row = wn * 32 + n * 16 + r16;
        bu[kk][n] = *(const short8*)(lBu + row * 64 + ((cb ^ (row & 7)) << 3));
      }
    }
    if (more) stG(nxt, kn);
    PRIO1();
#pragma unroll
    for (int kk = 0; kk < 2; kk++)
#pragma unroll
      for (int m = 0; m < 4; m++)
#pragma unroll
        for (int n = 0; n < 2; n++)
          accu[m][n] = __builtin_amdgcn_mfma_f32_16x16x32_bf16(af0[kk][m], bu[kk][n], accu[m][n], 0, 0, 0);
    PRIO0();

    // ---- P2: needs Ah1(t); MFMA(mh1,up); stage U(t+1) ----
    if (more) { WAITV4; } else { WAITV0; }
    BARC();
#pragma unroll
    for (int kk = 0; kk < 2; kk++) {
      const int cb = kk * 4 + c4;
#pragma unroll
      for (int m = 0; m < 4; m++) {
        int row = wm * 128 + 64 + m * 16 + r16;  // in A half1
        af1[kk][m] = *(const short8*)(lA + row * 64 + ((cb ^ (row & 7)) << 3));
      }
    }
    if (more) stU(nxt, kn);
    PRIO1();
#pragma unroll
    for (int kk = 0; kk < 2; kk++)
#pragma unroll
      for (int m = 0; m < 4; m++)
#pragma unroll
        for (int n = 0; n < 2; n++)
          accu[m + 4][n] = __builtin_amdgcn_mfma_f32_16x16x32_bf16(af1[kk][m], bu[kk][n], accu[m + 4][n], 0, 0, 0);
    PRIO0();

    // ---- P3: regs only; MFMA(mh1,gate); stage Ah1(t+1) ----
    BARC();
    if (more) stA(nxt, 1, kn);
    PRIO1();
#pragma unroll
    for (int kk = 0; kk < 2; kk++)
#pragma unroll
      for (int m = 0; m < 4; m++)
#pragma unroll
        for (int n = 0; n < 2; n++)
          accg[m + 4][n] = __builtin_amdgcn_mfma_f32_16x16x32_bf16(af1[kk][m], bg[kk][n], accg[m + 4][n], 0, 0, 0);
    PRIO0();
  }
  __syncthreads();

  // epilogue: silu(g)*u -> bf16, LDS repack, coalesced gathered store
  unsigned short* actL = smem;
  const int LSTR = 136;
#pragma unroll
  for (int m = 0; m < 8; m++) {
#pragma unroll
    for (int j = 0; j < 4; j++) {
      int row = wm * 128 + m * 16 + (c4 << 2) + j;
#pragma unroll
      for (int n = 0; n < 2; n++) {
        int col = wn * 32 + n * 16 + r16;
        float g = accg[m][n][j];
        float u = accu[m][n][j];
        float s = g / (1.f + __expf(-g));
        actL[row * LSTR + col] = f2bf(s * u);
      }
    }
  }
  __syncthreads();
#pragma unroll
  for (int i = 0; i < 8; i++) {
    int r = i * 32 + (tid >> 4);
    int ent = entL[r];
    if (ent >= 0) {
      int chunk = tid & 15;
      short8 v = *(const short8*)(actL + r * LSTR + chunk * 8);
      *(short8*)(act + (size_t)ent * ID + n0 + chunk * 8) = v;
    }
  }
}

// ------------- GEMM2: y[slot] = gate * (act[slot] @ wd) -------------
// 512 thr, BM=256, BN=256, 8 waves 2m x 4n, wave 128M x 64N.
// Stage units == phase read-sets:
//   A half h = rows {h*64+[0,63]} U {128+h*64+[0,63]}
//   B half h = rows {q*64 + h*32 + [0,31], q=0..3}
// Per-tile stage (into nxt): P0:Bh0  P1:Ah0  P2:Bh1  P3:Ah1. Steady waits vmcnt(4).
__global__ __launch_bounds__(512, 2) void gemm2_kernel(
    const unsigned short* __restrict__ act,
    const unsigned short* __restrict__ wdt,
    const int* __restrict__ counts,
    const int* __restrict__ list,
    const float* __restrict__ gates,
    unsigned short* __restrict__ yb,
    int BT) {
  const int e = blockIdx.z;
  const int ne = counts[e];
  const int m0 = blockIdx.y * 256;
  if (m0 >= ne) return;
  const int n0 = blockIdx.x * 256;

  __shared__ __align__(16) unsigned short smem[2 * 32768];  // 128 KB
  __shared__ int entL[256];
  __shared__ float gL[256];

  const int tid = threadIdx.x;
  const int lane = tid & 63;
  const int w = tid >> 6;

  if (tid < 256) {
    bool v = (m0 + tid < ne);
    entL[tid] = v ? list[e * BT + m0 + tid] : -1;
    gL[tid] = v ? gates[e * BT + m0 + tid] : 0.f;
  }
  __syncthreads();

  const int rsub = lane >> 3;
  const int swz = (lane & 7) ^ rsub;

  const unsigned short* aA[4];       // rows i*64 + w*8 + rsub
  const unsigned short* aB2[2][2];   // [h][j]: rows (j*2+(w>>2))*64 + h*32 + (w&3)*8 + rsub
  const unsigned short* dB = wdt + (size_t)e * HD * ID;
#pragma unroll
  for (int i = 0; i < 4; i++) {
    int r = i * 64 + w * 8 + rsub;
    int ent = entL[r];
    int slot = ent >= 0 ? ent : 0;
    aA[i] = act + (size_t)slot * ID + swz * 8;
  }
  const int q0 = w >> 2;                  // 0..1
  const int rq = (w & 3) * 8 + rsub;      // 0..31
#pragma unroll
  for (int hh = 0; hh < 2; hh++)
#pragma unroll
    for (int j = 0; j < 2; j++) {
      int r = (j * 2 + q0) * 64 + hh * 32 + rq;
      aB2[hh][j] = dB + (size_t)(n0 + r) * ID + swz * 8;
    }

  const int wm = w >> 2, wn = w & 3;
  const int r16 = lane & 15, c4 = lane >> 4;

  f32x4 acc[8][4];
#pragma unroll
  for (int m = 0; m < 8; m++)
#pragma unroll
    for (int n = 0; n < 4; n++) acc[m][n] = f32x4{0.f, 0.f, 0.f, 0.f};

  auto stA = [&](int b, int h, int koff) {
    unsigned short* base = smem + b * 32768;
    GLL(aA[h] + koff,     base + ((h * 64) + w * 8) * 64);
    GLL(aA[h + 2] + koff, base + ((128 + h * 64) + w * 8) * 64);
  };
  auto stB = [&](int b, int h, int koff) {
    unsigned short* base = smem + b * 32768 + 16384;
    GLL(aB2[h][0] + koff, base + ((q0 * 64 + h * 32 + (w & 3) * 8)) * 64);
    GLL(aB2[h][1] + koff, base + (((2 + q0) * 64 + h * 32 + (w & 3) * 8)) * 64);
  };

  // prologue: FIFO order Bh0(0), Ah0(0), Bh1(0), Ah1(0) = 8 loads
  stB(0, 0, 0); stA(0, 0, 0); stB(0, 1, 0); stA(0, 1, 0);

#pragma unroll 1
  for (int t = 0; t < ID / 64; ++t) {
    const int cur = t & 1, nxt = cur ^ 1;
    const int kn = t * 64 + 64;
    const bool more = (t < ID / 64 - 1);
    const unsigned short* lA = smem + cur * 32768;
    const unsigned short* lB = lA + 16384;

    short8 af0[2][4], af1[2][4], bf0[2][2], bf1[2][2];

    // ---- P0: needs Bh0(t)+Ah0(t); MFMA(mh0,nh0); stage Bh0(t+1) ----
    WAITV4; BARC();
#pragma unroll
    for (int kk = 0; kk < 2; kk++) {
      const int cb = kk * 4 + c4;
#pragma unroll
      for (int m = 0; m < 4; m++) {
        int row = wm * 128 + m * 16 + r16;        // A half0
        af0[kk][m] = *(const short8*)(lA + row * 64 + ((cb ^ (row & 7)) << 3));
      }
#pragma unroll
      for (int n = 0; n < 2; n++) {
        int row = wn * 64 + n * 16 + r16;         // B half0 stripe
        bf0[kk][n] = *(const short8*)(lB + row * 64 + ((cb ^ (row & 7)) << 3));
      }
    }
    if (more) stB(nxt, 0, kn);
    PRIO1();
#pragma unroll
    for (int kk = 0; kk < 2; kk++)
#pragma unroll
      for (int m = 0; m < 4; m++)
#pragma unroll
        for (int n = 0; n < 2; n++)
          acc[m][n] = __builtin_amdgcn_mfma_f32_16x16x32_bf16(af0[kk][m], bf0[kk][n], acc[m][n], 0, 0, 0);
    PRIO0();

    // ---- P1: needs Bh1(t); MFMA(mh0,nh1); stage Ah0(t+1) ----
    if (more) { WAITV4; } else { WAITV2; }
    BARC();
#pragma unroll
    for (int kk = 0; kk < 2; kk++) {
      const int cb = kk * 4 + c4;
#pragma unroll
      for (int n = 0; n < 2; n++) {
        int row = wn * 64 + 32 + n * 16 + r16;    // B half1 stripe
        bf1[kk][n] = *(const short8*)(lB + row * 64 + ((cb ^ (row & 7)) << 3));
      }
    }
    if (more) stA(nxt, 0, kn);
    PRIO1();
#pragma unroll
    for (int kk = 0; kk < 2; kk++)
#pragma unroll
      for (int m = 0; m < 4; m++)
#pragma unroll
        for (int n = 0; n < 2; n++)
          acc[m][n + 2] = __builtin_amdgcn_mfma_f32_16x16x32_bf16(af0[kk][m], bf1[kk][n], acc[m][n + 2], 0, 0, 0);
    PRIO0();

    // ---- P2: needs Ah1(t); MFMA(mh1,nh1); stage Bh1(t+1) ----
    if (more) { WAITV4; } else { WAITV0; }
    BARC();
#pragma unroll
    for (int kk = 0; kk < 2; kk++) {
      const int cb = kk * 4 + c4;
#pragma unroll
      for (int m = 0; m < 4; m++) {
        int row = wm * 128 + 64 + m * 16 + r16;   // A half1
        af1[kk][m] = *(const short8*)(lA + row * 64 + ((cb ^ (row & 7)) << 3));
      }
    }
    if (more) stB(nxt, 1, kn);
    PRIO1();
#pragma unroll
    for (int kk = 0; kk < 2; kk++)
#pragma unroll
      for (int m = 0; m < 4; m++)
#pragma unroll
        for (int n = 0; n < 2; n++)
          acc[m + 4][n + 2] = __builtin_amdgcn_mfma_f32_16x16x32_bf16(af1[kk][m], bf1[kk][n], acc[m + 4][n + 2], 0, 0, 0);
    PRIO0();

    // ---- P3: regs only; MFMA(mh1,nh0); stage Ah1(t+1) ----
    BARC();
    if (more) stA(nxt, 1, kn);
    PRIO1();
#pragma unroll
    for (int kk = 0; kk < 2; kk++)
#pragma unroll
      for (int m = 0; m < 4; m++)
#pragma unroll
        for (int n = 0; n < 2; n++)
          acc[m + 4][n] = __builtin_amdgcn_mfma_f32_16x16x32_bf16(af1[kk][m], bf0[kk][n], acc[m + 4][n], 0, 0, 0);
    PRIO0();
  }
  __syncthreads();

  // epilogue: scale by gate, bf16, 2-pass LDS repack, coalesced store
  unsigned short* yL = smem;
  const int LSTR2 = 264;
#pragma unroll 1
  for (int p = 0; p < 2; p++) {
    if (wm == p) {
#pragma unroll
      for (int m = 0; m < 8; m++) {
#pragma unroll
        for (int j = 0; j < 4; j++) {
          int row = m * 16 + (c4 << 2) + j;
          float gt = gL[p * 128 + row];
#pragma unroll
          for (int n = 0; n < 4; n++) {
            int col = wn * 64 + n * 16 + r16;
            yL[row * LSTR2 + col] = f2bf(acc[m][n][j] * gt);
          }
        }
      }
    }
    __syncthreads();
#pragma unroll
    for (int i = 0; i < 8; i++) {
      int r = i * 16 + (tid >> 5);
      int ent = entL[p * 128 + r];
      if (ent >= 0) {
        int chunk = tid & 31;
        short8 v = *(const short8*)(yL + r * LSTR2 + chunk * 8);
        *(short8*)(yb + (size_t)ent * HD + n0 + chunk * 8) = v;
      }
    }
    __syncthreads();
  }
}

// ------------- combine: out[t] = y[2t] + y[2t+1] (fp32) -------------
__global__ __launch_bounds__(256) void combine_kernel(const unsigned short* __restrict__ y,
                                                      float* __restrict__ out, int n8) {
  int i = blockIdx.x * 256 + threadIdx.x;
  if (i >= n8) return;
  int t = i >> 7;
  int c = (i & 127) * 8;
  short8 a = *(const short8*)(y + (size_t)(t * 2) * HD + c);
  short8 b = *(const short8*)(y + (size_t)(t * 2 + 1) * HD + c);
  float o[8];
#pragma unroll
  for (int j = 0; j < 8; j++)
    o[j] = bf2f((unsigned short)a[j]) + bf2f((unsigned short)b[j]);
  float* op = out + (size_t)t * HD + c;
  *(float4*)op = float4{o[0], o[1], o[2], o[3]};
  *(float4*)(op + 4) = float4{o[4], o[5], o[6], o[7]};
}

extern "C" void kernel_launch(void* const* d_in, const int* in_sizes, int n_in,
                              void* d_out, int out_size, void* d_ws, size_t ws_size,
                              hipStream_t stream) {
  (void)n_in; (void)ws_size; (void)out_size;
  const float* h  = (const float*)d_in[0];
  const float* gw = (const float*)d_in[1];
  const float* wg = (const float*)d_in[2];
  const float* wu = (const float*)d_in[3];
  const float* wd = (const float*)d_in[4];
  float* out = (float*)d_out;
  const int BT = in_sizes[0] / HD;

  char* ws = (char*)d_ws;
  size_t off = 0;
  auto alloc = [&](size_t b) -> char* {
    char* p = ws + off;
    off = (off + b + 255) & ~(size_t)255;
    return p;
  };
  unsigned short* hbf = (unsigned short*)alloc((size_t)BT * HD * 2);
  unsigned short* wgt = (unsigned short*)alloc((size_t)NE * HD * ID * 2);
  unsigned short* wut = (unsigned short*)alloc((size_t)NE * HD * ID * 2);
  unsigned short* wdt = (unsigned short*)alloc((size_t)NE * HD * ID * 2);
  unsigned short* act = (unsigned short*)alloc((size_t)BT * 2 * ID * 2);
  int* counts = (int*)alloc(NE * 4);
  int* list = (int*)alloc((size_t)NE * BT * 4);
  float* gates = (float*)alloc((size_t)NE * BT * 4);
  // y ([BT*2][HD] bf16 = 64 MB) aliases wgt+wut (dead after gemm1; rewritten
  // by tconv every call, so no cross-call state).
  unsigned short* yb = wgt;

  hipMemsetAsync(counts, 0, NE * 4, stream);

  cvt_kernel<<<(BT * HD / 8 + 255) / 256, 256, 0, stream>>>(h, hbf, BT * HD / 8);
  tconv_kernel<<<dim3(ID / 64, HD / 64, NE), 256, 0, stream>>>(wg, wgt, HD, ID);
  tconv_kernel<<<dim3(ID / 64, HD / 64, NE), 256, 0, stream>>>(wu, wut, HD, ID);
  tconv_kernel<<<dim3(HD / 64, ID / 64, NE), 256, 0, stream>>>(wd, wdt, ID, HD);
  router_kernel<<<BT / 4, 256, 0, stream>>>(h, gw, counts, list, gates, BT);
  gemm1_kernel<<<dim3(ID / 128, (BT + 255) / 256, NE), 512, 0, stream>>>(hbf, wgt, wut, counts, list, act, BT);
  gemm2_kernel<<<dim3(HD / 256, (BT + 255) / 256, NE), 512, 0, stream>>>(act, wdt, counts, list, gates, yb, BT);
  combine_kernel<<<(BT * HD / 8 + 255) / 256, 256, 0, stream>>>(yb, out, BT * HD / 8);
}

// Round 5
// 814.103 us; speedup vs baseline: 1.9096x; 1.4713x over previous
//
#include <hip/hip_runtime.h>
#include <stdint.h>

#define NE 8
#define HD 1024
#define ID 2048

typedef __attribute__((ext_vector_type(8))) short short8;
typedef __attribute__((ext_vector_type(4))) float f32x4;
typedef __attribute__((ext_vector_type(4))) unsigned short us4;

__device__ __forceinline__ unsigned short f2bf(float f) {
  uint32_t u = __builtin_bit_cast(uint32_t, f);
  u += 0x7fffu + ((u >> 16) & 1u);
  return (unsigned short)(u >> 16);
}
__device__ __forceinline__ float bf2f(unsigned short s) {
  uint32_t u = ((uint32_t)s) << 16;
  return __builtin_bit_cast(float, u);
}

// ------------- f32 [E][R][C] -> bf16 [E][C][R] transpose-convert -------------
__global__ __launch_bounds__(256) void tconv_kernel(const float* __restrict__ in,
                                                    unsigned short* __restrict__ out,
                                                    int R, int C) {
  __shared__ float t[64][65];
  int e = blockIdx.z;
  const float* ip = in + (size_t)e * R * C;
  unsigned short* op = out + (size_t)e * R * C;
  int c0 = blockIdx.x * 64, r0 = blockIdx.y * 64;
  int tid = threadIdx.x;
  int rr = tid >> 4;
  int cc = (tid & 15) * 4;
#pragma unroll
  for (int p = 0; p < 4; p++) {
    int r = p * 16 + rr;
    float4 v = *(const float4*)(ip + (size_t)(r0 + r) * C + c0 + cc);
    t[r][cc] = v.x; t[r][cc + 1] = v.y; t[r][cc + 2] = v.z; t[r][cc + 3] = v.w;
  }
  __syncthreads();
#pragma unroll
  for (int p = 0; p < 4; p++) {
    int c = p * 16 + rr;
    int r = cc;
    unsigned short tmp[4];
    tmp[0] = f2bf(t[r][c]); tmp[1] = f2bf(t[r + 1][c]);
    tmp[2] = f2bf(t[r + 2][c]); tmp[3] = f2bf(t[r + 3][c]);
    *(us4*)(op + (size_t)(c0 + c) * R + r0 + r) = *(us4*)tmp;
  }
}

// ---- router stage 1: logits + top2 + gates (NO global atomics); fused h->bf16 ----
// 256 thr = 4 waves; block handles 16 tokens (4 per wave, serial).
__global__ __launch_bounds__(256) void router_compute(
    const float* __restrict__ h, const float* __restrict__ gw,
    unsigned short* __restrict__ hbf, uint32_t* __restrict__ eidx,
    float2* __restrict__ gpair, int BT) {
  __shared__ float gwl[NE * HD];  // 32 KB
  int tid = threadIdx.x;
  for (int i = tid * 4; i < NE * HD; i += 256 * 4) {
    float4 v = *(const float4*)(gw + i);
    gwl[i] = v.x; gwl[i + 1] = v.y; gwl[i + 2] = v.z; gwl[i + 3] = v.w;
  }
  __syncthreads();
  int wid = tid >> 6, lane = tid & 63;
#pragma unroll 1
  for (int tt = 0; tt < 4; tt++) {
    int t = blockIdx.x * 16 + wid * 4 + tt;
    if (t >= BT) continue;
    const float* hp = h + (size_t)t * HD;
    float4 hv[4];
#pragma unroll
    for (int j = 0; j < 4; j++) hv[j] = ((const float4*)hp)[lane + 64 * j];
    // fused h -> bf16 store
#pragma unroll
    for (int j = 0; j < 4; j++) {
      unsigned short tmp[4] = {f2bf(hv[j].x), f2bf(hv[j].y), f2bf(hv[j].z), f2bf(hv[j].w)};
      *(us4*)(hbf + (size_t)t * HD + (lane + 64 * j) * 4) = *(us4*)tmp;
    }
    float acc[NE];
#pragma unroll
    for (int e = 0; e < NE; e++) {
      float s = 0.f;
#pragma unroll
      for (int j = 0; j < 4; j++) {
        float4 g = *(const float4*)(gwl + e * HD + (lane + 64 * j) * 4);
        s += hv[j].x * g.x + hv[j].y * g.y + hv[j].z * g.z + hv[j].w * g.w;
      }
      acc[e] = s;
    }
#pragma unroll
    for (int e = 0; e < NE; e++) {
#pragma unroll
      for (int off = 32; off; off >>= 1) acc[e] += __shfl_xor(acc[e], off);
    }
    if (lane == 0) {
      int i0 = 0; float m0v = acc[0];
#pragma unroll
      for (int e = 1; e < NE; e++) if (acc[e] > m0v) { m0v = acc[e]; i0 = e; }
      int i1 = -1; float m1v = -3.4e38f;
#pragma unroll
      for (int e = 0; e < NE; e++) if (e != i0 && acc[e] > m1v) { m1v = acc[e]; i1 = e; }
      float d = __expf(m1v - m0v);
      float g0 = 1.f / (1.f + d);
      float g1 = d / (1.f + d);
      eidx[t] = (uint32_t)i0 | ((uint32_t)i1 << 8);
      gpair[t] = make_float2(g0, g1);
    }
  }
}

// ---- router stage 2: per-block LDS histogram -> 8 global atomics/block ----
__global__ __launch_bounds__(256) void router_scatter(
    const uint32_t* __restrict__ eidx, const float2* __restrict__ gpair,
    int* __restrict__ counts, int* __restrict__ list, float* __restrict__ gates,
    int BT) {
  __shared__ int lcnt[NE];
  __shared__ int lbase[NE];
  int tid = threadIdx.x;
  if (tid < NE) lcnt[tid] = 0;
  __syncthreads();
  int t = blockIdx.x * 256 + tid;
  int e0 = 0, e1 = 0, p0 = 0, p1 = 0;
  float2 g = make_float2(0.f, 0.f);
  bool v = (t < BT);
  if (v) {
    uint32_t ei = eidx[t];
    e0 = ei & 0xff; e1 = (ei >> 8) & 0xff;
    g = gpair[t];
    p0 = atomicAdd(&lcnt[e0], 1);
    p1 = atomicAdd(&lcnt[e1], 1);
  }
  __syncthreads();
  if (tid < NE) lbase[tid] = atomicAdd(&counts[tid], lcnt[tid]);
  __syncthreads();
  if (v) {
    int o0 = e0 * BT + lbase[e0] + p0;
    list[o0] = t * 2;     gates[o0] = g.x;
    int o1 = e1 * BT + lbase[e1] + p1;
    list[o1] = t * 2 + 1; gates[o1] = g.y;
  }
}

#define GLL(gsrc, ldst)                                                        \
  __builtin_amdgcn_global_load_lds(                                            \
      (const __attribute__((address_space(1))) void*)(gsrc),                   \
      (__attribute__((address_space(3))) void*)(ldst), 16, 0, 0)

#define WAITV4 asm volatile("s_waitcnt vmcnt(4)" ::: "memory")
#define WAITV2 asm volatile("s_waitcnt vmcnt(2)" ::: "memory")
#define WAITV0 asm volatile("s_waitcnt vmcnt(0)" ::: "memory")
#define BARC()  do { __builtin_amdgcn_s_barrier(); asm volatile("" ::: "memory"); } while (0)
#define PRIO1() __builtin_amdgcn_s_setprio(1)
#define PRIO0() __builtin_amdgcn_s_setprio(0)

// ------------- GEMM1: act[slot] = silu(h@wg)*(h@wu) -------------
// 512 thr, BM=256, BN=128 dual, 8 waves 2m x 4n, wave 128M x 32N per type.
// 4-phase counted-vmcnt. Stage units == phase read-sets:
//   A half h = rows {h*64+[0,63]} U {128+h*64+[0,63]}  (af0 reads h=0, af1 h=1)
//   G, U full 128-row tiles.
// Per-tile stage (into nxt): P0:Ah0  P1:G  P2:U  P3:Ah1. Steady waits vmcnt(4).
__global__ __launch_bounds__(512, 2) void gemm1_kernel(
    const unsigned short* __restrict__ hbf,
    const unsigned short* __restrict__ wgt,
    const unsigned short* __restrict__ wut,
    const int* __restrict__ counts,
    const int* __restrict__ list,
    unsigned short* __restrict__ act,
    int BT) {
  const int e = blockIdx.z;
  const int ne = counts[e];
  const int m0 = blockIdx.y * 256;
  if (m0 >= ne) return;
  const int n0 = blockIdx.x * 128;

  __shared__ __align__(16) unsigned short smem[2 * 32768];  // 128 KB
  __shared__ int entL[256];

  const int tid = threadIdx.x;
  const int lane = tid & 63;
  const int w = tid >> 6;

  if (tid < 256) entL[tid] = (m0 + tid < ne) ? list[e * BT + m0 + tid] : -1;
  __syncthreads();

  const int rsub = lane >> 3;
  const int swz = (lane & 7) ^ rsub;

  const unsigned short* aA[4];   // aA[i]: rows i*64 + w*8 + rsub
  const unsigned short* aG[2];
  const unsigned short* aU[2];
  const unsigned short* gB = wgt + (size_t)e * ID * HD;
  const unsigned short* uB = wut + (size_t)e * ID * HD;
#pragma unroll
  for (int i = 0; i < 4; i++) {
    int r = i * 64 + w * 8 + rsub;
    int ent = entL[r];
    int tok = ent >= 0 ? (ent >> 1) : 0;
    aA[i] = hbf + (size_t)tok * HD + swz * 8;
  }
#pragma unroll
  for (int i = 0; i < 2; i++) {
    int r = i * 64 + w * 8 + rsub;
    aG[i] = gB + (size_t)(n0 + r) * HD + swz * 8;
    aU[i] = uB + (size_t)(n0 + r) * HD + swz * 8;
  }

  const int wm = w >> 2, wn = w & 3;
  const int r16 = lane & 15, c4 = lane >> 4;

  f32x4 accg[8][2], accu[8][2];
#pragma unroll
  for (int m = 0; m < 8; m++)
#pragma unroll
    for (int n = 0; n < 2; n++) {
      accg[m][n] = f32x4{0.f, 0.f, 0.f, 0.f};
      accu[m][n] = f32x4{0.f, 0.f, 0.f, 0.f};
    }

  auto stA = [&](int b, int h, int koff) {
    unsigned short* base = smem + b * 32768;
    GLL(aA[h] + koff,     base + ((h * 64) + w * 8) * 64);
    GLL(aA[h + 2] + koff, base + ((128 + h * 64) + w * 8) * 64);
  };
  auto stG = [&](int b, int koff) {
    unsigned short* base = smem + b * 32768 + 16384 + (w * 8) * 64;
    GLL(aG[0] + koff, base);
    GLL(aG[1] + koff, base + 4096);
  };
  auto stU = [&](int b, int koff) {
    unsigned short* base = smem + b * 32768 + 24576 + (w * 8) * 64;
    GLL(aU[0] + koff, base);
    GLL(aU[1] + koff, base + 4096);
  };

  // prologue: FIFO order Ah0(0), G(0), U(0), Ah1(0) = 8 loads
  stA(0, 0, 0); stG(0, 0); stU(0, 0); stA(0, 1, 0);

#pragma unroll 1
  for (int t = 0; t < HD / 64; ++t) {
    const int cur = t & 1, nxt = cur ^ 1;
    const int kn = t * 64 + 64;
    const bool more = (t < HD / 64 - 1);
    const unsigned short* lA = smem + cur * 32768;
    const unsigned short* lBg = lA + 16384;
    const unsigned short* lBu = lA + 24576;

    short8 af0[2][4], af1[2][4], bg[2][2], bu[2][2];

    // ---- P0: needs Ah0(t)+G(t); MFMA(mh0,gate); stage Ah0(t+1) ----
    WAITV4; BARC();
#pragma unroll
    for (int kk = 0; kk < 2; kk++) {
      const int cb = kk * 4 + c4;
#pragma unroll
      for (int m = 0; m < 4; m++) {
        int row = wm * 128 + m * 16 + r16;   // in A half0
        af0[kk][m] = *(const short8*)(lA + row * 64 + ((cb ^ (row & 7)) << 3));
      }
#pragma unroll
      for (int n = 0; n < 2; n++) {
        int row = wn * 32 + n * 16 + r16;
        bg[kk][n] = *(const short8*)(lBg + row * 64 + ((cb ^ (row & 7)) << 3));
      }
    }
    if (more) stA(nxt, 0, kn);
    PRIO1();
#pragma unroll
    for (int kk = 0; kk < 2; kk++)
#pragma unroll
      for (int m = 0; m < 4; m++)
#pragma unroll
        for (int n = 0; n < 2; n++)
          accg[m][n] = __builtin_amdgcn_mfma_f32_16x16x32_bf16(af0[kk][m], bg[kk][n], accg[m][n], 0, 0, 0);
    PRIO0();

    // ---- P1: needs U(t); MFMA(mh0,up); stage G(t+1) ----
    if (more) { WAITV4; } else { WAITV2; }
    BARC();
#pragma unroll
    for (int kk = 0; kk < 2; kk++) {
      const int cb = kk * 4 + c4;
#pragma unroll
      for (int n = 0; n < 2; n++) {
        int row = wn * 32 + n * 16 + r16;
        bu[kk][n] = *(const short8*)(lBu + row * 64 + ((cb ^ (row & 7)) << 3));
      }
    }
    if (more) stG(nxt, kn);
    PRIO1();
#pragma unroll
    for (int kk = 0; kk < 2; kk++)
#pragma unroll
      for (int m = 0; m < 4; m++)
#pragma unroll
        for (int n = 0; n < 2; n++)
          accu[m][n] = __builtin_amdgcn_mfma_f32_16x16x32_bf16(af0[kk][m], bu[kk][n], accu[m][n], 0, 0, 0);
    PRIO0();

    // ---- P2: needs Ah1(t); MFMA(mh1,up); stage U(t+1) ----
    if (more) { WAITV4; } else { WAITV0; }
    BARC();
#pragma unroll
    for (int kk = 0; kk < 2; kk++) {
      const int cb = kk * 4 + c4;
#pragma unroll
      for (int m = 0; m < 4; m++) {
        int row = wm * 128 + 64 + m * 16 + r16;  // in A half1
        af1[kk][m] = *(const short8*)(lA + row * 64 + ((cb ^ (row & 7)) << 3));
      }
    }
    if (more) stU(nxt, kn);
    PRIO1();
#pragma unroll
    for (int kk = 0; kk < 2; kk++)
#pragma unroll
      for (int m = 0; m < 4; m++)
#pragma unroll
        for (int n = 0; n < 2; n++)
          accu[m + 4][n] = __builtin_amdgcn_mfma_f32_16x16x32_bf16(af1[kk][m], bu[kk][n], accu[m + 4][n], 0, 0, 0);
    PRIO0();

    // ---- P3: regs only; MFMA(mh1,gate); stage Ah1(t+1) ----
    BARC();
    if (more) stA(nxt, 1, kn);
    PRIO1();
#pragma unroll
    for (int kk = 0; kk < 2; kk++)
#pragma unroll
      for (int m = 0; m < 4; m++)
#pragma unroll
        for (int n = 0; n < 2; n++)
          accg[m + 4][n] = __builtin_amdgcn_mfma_f32_16x16x32_bf16(af1[kk][m], bg[kk][n], accg[m + 4][n], 0, 0, 0);
    PRIO0();
  }
  __syncthreads();

  // epilogue: silu(g)*u -> bf16, LDS repack, coalesced gathered store
  unsigned short* actL = smem;
  const int LSTR = 136;
#pragma unroll
  for (int m = 0; m < 8; m++) {
#pragma unroll
    for (int j = 0; j < 4; j++) {
      int row = wm * 128 + m * 16 + (c4 << 2) + j;
#pragma unroll
      for (int n = 0; n < 2; n++) {
        int col = wn * 32 + n * 16 + r16;
        float g = accg[m][n][j];
        float u = accu[m][n][j];
        float s = g / (1.f + __expf(-g));
        actL[row * LSTR + col] = f2bf(s * u);
      }
    }
  }
  __syncthreads();
#pragma unroll
  for (int i = 0; i < 8; i++) {
    int r = i * 32 + (tid >> 4);
    int ent = entL[r];
    if (ent >= 0) {
      int chunk = tid & 15;
      short8 v = *(const short8*)(actL + r * LSTR + chunk * 8);
      *(short8*)(act + (size_t)ent * ID + n0 + chunk * 8) = v;
    }
  }
}

// ------------- GEMM2: y[slot] = gate * (act[slot] @ wd) -------------
// 512 thr, BM=256, BN=256, 8 waves 2m x 4n, wave 128M x 64N.
// Stage units == phase read-sets:
//   A half h = rows {h*64+[0,63]} U {128+h*64+[0,63]}
//   B half h = rows {q*64 + h*32 + [0,31], q=0..3}
// Per-tile stage (into nxt): P0:Bh0  P1:Ah0  P2:Bh1  P3:Ah1. Steady waits vmcnt(4).
__global__ __launch_bounds__(512, 2) void gemm2_kernel(
    const unsigned short* __restrict__ act,
    const unsigned short* __restrict__ wdt,
    const int* __restrict__ counts,
    const int* __restrict__ list,
    const float* __restrict__ gates,
    unsigned short* __restrict__ yb,
    int BT) {
  const int e = blockIdx.z;
  const int ne = counts[e];
  const int m0 = blockIdx.y * 256;
  if (m0 >= ne) return;
  const int n0 = blockIdx.x * 256;

  __shared__ __align__(16) unsigned short smem[2 * 32768];  // 128 KB
  __shared__ int entL[256];
  __shared__ float gL[256];

  const int tid = threadIdx.x;
  const int lane = tid & 63;
  const int w = tid >> 6;

  if (tid < 256) {
    bool v = (m0 + tid < ne);
    entL[tid] = v ? list[e * BT + m0 + tid] : -1;
    gL[tid] = v ? gates[e * BT + m0 + tid] : 0.f;
  }
  __syncthreads();

  const int rsub = lane >> 3;
  const int swz = (lane & 7) ^ rsub;

  const unsigned short* aA[4];       // rows i*64 + w*8 + rsub
  const unsigned short* aB2[2][2];   // [h][j]: rows (j*2+(w>>2))*64 + h*32 + (w&3)*8 + rsub
  const unsigned short* dB = wdt + (size_t)e * HD * ID;
#pragma unroll
  for (int i = 0; i < 4; i++) {
    int r = i * 64 + w * 8 + rsub;
    int ent = entL[r];
    int slot = ent >= 0 ? ent : 0;
    aA[i] = act + (size_t)slot * ID + swz * 8;
  }
  const int q0 = w >> 2;                  // 0..1
  const int rq = (w & 3) * 8 + rsub;      // 0..31
#pragma unroll
  for (int hh = 0; hh < 2; hh++)
#pragma unroll
    for (int j = 0; j < 2; j++) {
      int r = (j * 2 + q0) * 64 + hh * 32 + rq;
      aB2[hh][j] = dB + (size_t)(n0 + r) * ID + swz * 8;
    }

  const int wm = w >> 2, wn = w & 3;
  const int r16 = lane & 15, c4 = lane >> 4;

  f32x4 acc[8][4];
#pragma unroll
  for (int m = 0; m < 8; m++)
#pragma unroll
    for (int n = 0; n < 4; n++) acc[m][n] = f32x4{0.f, 0.f, 0.f, 0.f};

  auto stA = [&](int b, int h, int koff) {
    unsigned short* base = smem + b * 32768;
    GLL(aA[h] + koff,     base + ((h * 64) + w * 8) * 64);
    GLL(aA[h + 2] + koff, base + ((128 + h * 64) + w * 8) * 64);
  };
  auto stB = [&](int b, int h, int koff) {
    unsigned short* base = smem + b * 32768 + 16384;
    GLL(aB2[h][0] + koff, base + ((q0 * 64 + h * 32 + (w & 3) * 8)) * 64);
    GLL(aB2[h][1] + koff, base + (((2 + q0) * 64 + h * 32 + (w & 3) * 8)) * 64);
  };

  // prologue: FIFO order Bh0(0), Ah0(0), Bh1(0), Ah1(0) = 8 loads
  stB(0, 0, 0); stA(0, 0, 0); stB(0, 1, 0); stA(0, 1, 0);

#pragma unroll 1
  for (int t = 0; t < ID / 64; ++t) {
    const int cur = t & 1, nxt = cur ^ 1;
    const int kn = t * 64 + 64;
    const bool more = (t < ID / 64 - 1);
    const unsigned short* lA = smem + cur * 32768;
    const unsigned short* lB = lA + 16384;

    short8 af0[2][4], af1[2][4], bf0[2][2], bf1[2][2];

    // ---- P0: needs Bh0(t)+Ah0(t); MFMA(mh0,nh0); stage Bh0(t+1) ----
    WAITV4; BARC();
#pragma unroll
    for (int kk = 0; kk < 2; kk++) {
      const int cb = kk * 4 + c4;
#pragma unroll
      for (int m = 0; m < 4; m++) {
        int row = wm * 128 + m * 16 + r16;        // A half0
        af0[kk][m] = *(const short8*)(lA + row * 64 + ((cb ^ (row & 7)) << 3));
      }
#pragma unroll
      for (int n = 0; n < 2; n++) {
        int row = wn * 64 + n * 16 + r16;         // B half0 stripe
        bf0[kk][n] = *(const short8*)(lB + row * 64 + ((cb ^ (row & 7)) << 3));
      }
    }
    if (more) stB(nxt, 0, kn);
    PRIO1();
#pragma unroll
    for (int kk = 0; kk < 2; kk++)
#pragma unroll
      for (int m = 0; m < 4; m++)
#pragma unroll
        for (int n = 0; n < 2; n++)
          acc[m][n] = __builtin_amdgcn_mfma_f32_16x16x32_bf16(af0[kk][m], bf0[kk][n], acc[m][n], 0, 0, 0);
    PRIO0();

    // ---- P1: needs Bh1(t); MFMA(mh0,nh1); stage Ah0(t+1) ----
    if (more) { WAITV4; } else { WAITV2; }
    BARC();
#pragma unroll
    for (int kk = 0; kk < 2; kk++) {
      const int cb = kk * 4 + c4;
#pragma unroll
      for (int n = 0; n < 2; n++) {
        int row = wn * 64 + 32 + n * 16 + r16;    // B half1 stripe
        bf1[kk][n] = *(const short8*)(lB + row * 64 + ((cb ^ (row & 7)) << 3));
      }
    }
    if (more) stA(nxt, 0, kn);
    PRIO1();
#pragma unroll
    for (int kk = 0; kk < 2; kk++)
#pragma unroll
      for (int m = 0; m < 4; m++)
#pragma unroll
        for (int n = 0; n < 2; n++)
          acc[m][n + 2] = __builtin_amdgcn_mfma_f32_16x16x32_bf16(af0[kk][m], bf1[kk][n], acc[m][n + 2], 0, 0, 0);
    PRIO0();

    // ---- P2: needs Ah1(t); MFMA(mh1,nh1); stage Bh1(t+1) ----
    if (more) { WAITV4; } else { WAITV0; }
    BARC();
#pragma unroll
    for (int kk = 0; kk < 2; kk++) {
      const int cb = kk * 4 + c4;
#pragma unroll
      for (int m = 0; m < 4; m++) {
        int row = wm * 128 + 64 + m * 16 + r16;   // A half1
        af1[kk][m] = *(const short8*)(lA + row * 64 + ((cb ^ (row & 7)) << 3));
      }
    }
    if (more) stB(nxt, 1, kn);
    PRIO1();
#pragma unroll
    for (int kk = 0; kk < 2; kk++)
#pragma unroll
      for (int m = 0; m < 4; m++)
#pragma unroll
        for (int n = 0; n < 2; n++)
          acc[m + 4][n + 2] = __builtin_amdgcn_mfma_f32_16x16x32_bf16(af1[kk][m], bf1[kk][n], acc[m + 4][n + 2], 0, 0, 0);
    PRIO0();

    // ---- P3: regs only; MFMA(mh1,nh0); stage Ah1(t+1) ----
    BARC();
    if (more) stA(nxt, 1, kn);
    PRIO1();
#pragma unroll
    for (int kk = 0; kk < 2; kk++)
#pragma unroll
      for (int m = 0; m < 4; m++)
#pragma unroll
        for (int n = 0; n < 2; n++)
          acc[m + 4][n] = __builtin_amdgcn_mfma_f32_16x16x32_bf16(af1[kk][m], bf0[kk][n], acc[m + 4][n], 0, 0, 0);
    PRIO0();
  }
  __syncthreads();

  // epilogue: scale by gate, bf16, 2-pass LDS repack, coalesced store
  unsigned short* yL = smem;
  const int LSTR2 = 264;
#pragma unroll 1
  for (int p = 0; p < 2; p++) {
    if (wm == p) {
#pragma unroll
      for (int m = 0; m < 8; m++) {
#pragma unroll
        for (int j = 0; j < 4; j++) {
          int row = m * 16 + (c4 << 2) + j;
          float gt = gL[p * 128 + row];
#pragma unroll
          for (int n = 0; n < 4; n++) {
            int col = wn * 64 + n * 16 + r16;
            yL[row * LSTR2 + col] = f2bf(acc[m][n][j] * gt);
          }
        }
      }
    }
    __syncthreads();
#pragma unroll
    for (int i = 0; i < 8; i++) {
      int r = i * 16 + (tid >> 5);
      int ent = entL[p * 128 + r];
      if (ent >= 0) {
        int chunk = tid & 31;
        short8 v = *(const short8*)(yL + r * LSTR2 + chunk * 8);
        *(short8*)(yb + (size_t)ent * HD + n0 + chunk * 8) = v;
      }
    }
    __syncthreads();
  }
}

// ------------- combine: out[t] = y[2t] + y[2t+1] (fp32) -------------
__global__ __launch_bounds__(256) void combine_kernel(const unsigned short* __restrict__ y,
                                                      float* __restrict__ out, int n8) {
  int i = blockIdx.x * 256 + threadIdx.x;
  if (i >= n8) return;
  int t = i >> 7;
  int c = (i & 127) * 8;
  short8 a = *(const short8*)(y + (size_t)(t * 2) * HD + c);
  short8 b = *(const short8*)(y + (size_t)(t * 2 + 1) * HD + c);
  float o[8];
#pragma unroll
  for (int j = 0; j < 8; j++)
    o[j] = bf2f((unsigned short)a[j]) + bf2f((unsigned short)b[j]);
  float* op = out + (size_t)t * HD + c;
  *(float4*)op = float4{o[0], o[1], o[2], o[3]};
  *(float4*)(op + 4) = float4{o[4], o[5], o[6], o[7]};
}

extern "C" void kernel_launch(void* const* d_in, const int* in_sizes, int n_in,
                              void* d_out, int out_size, void* d_ws, size_t ws_size,
                              hipStream_t stream) {
  (void)n_in; (void)ws_size; (void)out_size;
  const float* h  = (const float*)d_in[0];
  const float* gw = (const float*)d_in[1];
  const float* wg = (const float*)d_in[2];
  const float* wu = (const float*)d_in[3];
  const float* wd = (const float*)d_in[4];
  float* out = (float*)d_out;
  const int BT = in_sizes[0] / HD;

  char* ws = (char*)d_ws;
  size_t off = 0;
  auto alloc = [&](size_t b) -> char* {
    char* p = ws + off;
    off = (off + b + 255) & ~(size_t)255;
    return p;
  };
  unsigned short* hbf = (unsigned short*)alloc((size_t)BT * HD * 2);
  unsigned short* wgt = (unsigned short*)alloc((size_t)NE * HD * ID * 2);
  unsigned short* wut = (unsigned short*)alloc((size_t)NE * HD * ID * 2);
  unsigned short* wdt = (unsigned short*)alloc((size_t)NE * HD * ID * 2);
  unsigned short* act = (unsigned short*)alloc((size_t)BT * 2 * ID * 2);
  int* counts = (int*)alloc(NE * 4);
  int* list = (int*)alloc((size_t)NE * BT * 4);
  float* gates = (float*)alloc((size_t)NE * BT * 4);
  uint32_t* eidx = (uint32_t*)alloc((size_t)BT * 4);
  float2* gpair = (float2*)alloc((size_t)BT * 8);
  // y ([BT*2][HD] bf16 = 64 MB) aliases wgt+wut (dead after gemm1; rewritten
  // by tconv every call, so no cross-call state).
  unsigned short* yb = wgt;

  hipMemsetAsync(counts, 0, NE * 4, stream);

  router_compute<<<BT / 16, 256, 0, stream>>>(h, gw, hbf, eidx, gpair, BT);
  router_scatter<<<(BT + 255) / 256, 256, 0, stream>>>(eidx, gpair, counts, list, gates, BT);
  tconv_kernel<<<dim3(ID / 64, HD / 64, NE), 256, 0, stream>>>(wg, wgt, HD, ID);
  tconv_kernel<<<dim3(ID / 64, HD / 64, NE), 256, 0, stream>>>(wu, wut, HD, ID);
  tconv_kernel<<<dim3(HD / 64, ID / 64, NE), 256, 0, stream>>>(wd, wdt, ID, HD);
  gemm1_kernel<<<dim3(ID / 128, (BT + 255) / 256, NE), 512, 0, stream>>>(hbf, wgt, wut, counts, list, act, BT);
  gemm2_kernel<<<dim3(HD / 256, (BT + 255) / 256, NE), 512, 0, stream>>>(act, wdt, counts, list, gates, yb, BT);
  combine_kernel<<<(BT * HD / 8 + 255) / 256, 256, 0, stream>>>(yb, out, BT * HD / 8);
}